// Round 3
// baseline (134.332 us; speedup 1.0000x reference)
//
#include <hip/hip_runtime.h>
#include <hip/hip_cooperative_groups.h>

namespace cg = cooperative_groups;

#define N_NODES 50000
#define N_EDGES 640000
#define D 128

// Raw clang vector types (work with __builtin_nontemporal_load/store,
// unlike HIP's class-wrapped float4).
typedef float f4 __attribute__((ext_vector_type(4)));
typedef int   i4 __attribute__((ext_vector_type(4)));

// Fused single cooperative kernel:
//  Phase 1: 16 lanes/node compute s1[n]=X[n]·W1, s2[n]=X[n]·W2.
//           X is read-once -> nontemporal loads (don't evict s1/s2 from L2).
//  grid.sync()
//  Phase 2: out[e] = s1[src[e]] + s2[dst[e]], 8 edges/thread.
//           Index streams nontemporal (read-once); s1/s2 gathers L2-hot;
//           output nontemporal (write-once).
__global__ __launch_bounds__(256) void fused_edge_decoder_kernel(
    const float* __restrict__ X,
    const int* __restrict__ src,
    const int* __restrict__ dst,
    const float* __restrict__ W1,
    const float* __restrict__ W2,
    float* __restrict__ s1,
    float* __restrict__ s2,
    float* __restrict__ out)
{
    const int lane = threadIdx.x & 63;
    const int sl   = lane & 15;                         // lane within 16-group
    const int wave = blockIdx.x * 4 + (threadIdx.x >> 6);
    const int g    = wave * 4 + (lane >> 4);            // global 16-lane group
    const int total_groups = gridDim.x * 16;

    // ---- Phase 1: node scores ----
    const f4* W1v = (const f4*)W1;
    const f4* W2v = (const f4*)W2;
    const f4 w1a = W1v[sl * 2], w1b = W1v[sl * 2 + 1];
    const f4 w2a = W2v[sl * 2], w2b = W2v[sl * 2 + 1];

    for (int n = g; n < N_NODES; n += total_groups) {
        const f4* Xv = (const f4*)(X + (size_t)n * D);
        const f4 x0 = __builtin_nontemporal_load(Xv + sl * 2);
        const f4 x1 = __builtin_nontemporal_load(Xv + sl * 2 + 1);
        float p1 = x0.x * w1a.x + x0.y * w1a.y + x0.z * w1a.z + x0.w * w1a.w
                 + x1.x * w1b.x + x1.y * w1b.y + x1.z * w1b.z + x1.w * w1b.w;
        float p2 = x0.x * w2a.x + x0.y * w2a.y + x0.z * w2a.z + x0.w * w2a.w
                 + x1.x * w2b.x + x1.y * w2b.y + x1.z * w2b.z + x1.w * w2b.w;
        #pragma unroll
        for (int off = 8; off > 0; off >>= 1) {
            p1 += __shfl_xor(p1, off, 64);
            p2 += __shfl_xor(p2, off, 64);
        }
        if (sl == 0) {
            s1[n] = p1;
            s2[n] = p2;
        }
    }

    // ---- Grid-wide barrier (device-scope; crosses XCD L2s) ----
    cg::this_grid().sync();

    // ---- Phase 2: edge combine, 8 edges/thread ----
    const int n8 = N_EDGES / 8;
    const int nthreads = gridDim.x * blockDim.x;
    for (int i = blockIdx.x * blockDim.x + threadIdx.x; i < n8; i += nthreads) {
        const i4 sa = __builtin_nontemporal_load((const i4*)src + 2 * i);
        const i4 sb = __builtin_nontemporal_load((const i4*)src + 2 * i + 1);
        const i4 da = __builtin_nontemporal_load((const i4*)dst + 2 * i);
        const i4 db = __builtin_nontemporal_load((const i4*)dst + 2 * i + 1);
        f4 oa, ob;
        oa.x = s1[sa.x] + s2[da.x];
        oa.y = s1[sa.y] + s2[da.y];
        oa.z = s1[sa.z] + s2[da.z];
        oa.w = s1[sa.w] + s2[da.w];
        ob.x = s1[sb.x] + s2[db.x];
        ob.y = s1[sb.y] + s2[db.y];
        ob.z = s1[sb.z] + s2[db.z];
        ob.w = s1[sb.w] + s2[db.w];
        __builtin_nontemporal_store(oa, (f4*)out + 2 * i);
        __builtin_nontemporal_store(ob, (f4*)out + 2 * i + 1);
    }
}

extern "C" void kernel_launch(void* const* d_in, const int* in_sizes, int n_in,
                              void* d_out, int out_size, void* d_ws, size_t ws_size,
                              hipStream_t stream) {
    const float* X  = (const float*)d_in[0];   // [N_NODES, D]
    const int*   ei = (const int*)d_in[1];     // [2, N_EDGES] (int32 on device)
    const float* W1 = (const float*)d_in[2];   // [1, D]
    const float* W2 = (const float*)d_in[3];   // [1, D]
    float* out = (float*)d_out;                // [N_EDGES, 1]

    float* s1 = (float*)d_ws;                  // [N_NODES]
    float* s2 = s1 + N_NODES;                  // [N_NODES]

    const int* src = ei;
    const int* dst = ei + N_EDGES;

    // 256 blocks x 256 threads = 4 waves/block -> trivially co-resident
    // (max 32 waves/CU); cooperative launch for the grid-wide sync.
    void* args[] = {(void*)&X, (void*)&src, (void*)&dst, (void*)&W1,
                    (void*)&W2, (void*)&s1, (void*)&s2, (void*)&out};
    hipLaunchCooperativeKernel((const void*)fused_edge_decoder_kernel,
                               dim3(256), dim3(256), args, 0, stream);
}

// Round 4
// 84.602 us; speedup vs baseline: 1.5878x; 1.5878x over previous
//
#include <hip/hip_runtime.h>

#define N_NODES 50000
#define N_EDGES 640000
#define D 128

// Kernel 1: 16 lanes per node (4 nodes per wave-iteration).
// Lane sl (0..15) loads X[n][sl*8 .. sl*8+7] as two float4 (32B/lane, 512B
// contiguous per node). Butterfly-reduce over 16 lanes: 4 steps x 2 dots.
__global__ __launch_bounds__(256) void node_scores_kernel(
    const float* __restrict__ X,
    const float* __restrict__ W1,
    const float* __restrict__ W2,
    float* __restrict__ s1,
    float* __restrict__ s2,
    int n_nodes, int total_groups)
{
    const int lane = threadIdx.x & 63;
    const int sl   = lane & 15;          // lane within 16-lane group
    const int sub  = lane >> 4;          // group within wave (0..3)
    const int wave = blockIdx.x * (blockDim.x >> 6) + (threadIdx.x >> 6);
    const int g    = wave * 4 + sub;     // global 16-lane group id

    // W fragments in registers for the whole kernel.
    const float4* W1v = (const float4*)W1;
    const float4* W2v = (const float4*)W2;
    const float4 w1a = W1v[sl * 2],     w1b = W1v[sl * 2 + 1];
    const float4 w2a = W2v[sl * 2],     w2b = W2v[sl * 2 + 1];

    for (int n = g; n < n_nodes; n += total_groups) {
        const float4* Xv = (const float4*)(X + (size_t)n * D);
        const float4 x0 = Xv[sl * 2];
        const float4 x1 = Xv[sl * 2 + 1];
        float p1 = x0.x * w1a.x + x0.y * w1a.y + x0.z * w1a.z + x0.w * w1a.w
                 + x1.x * w1b.x + x1.y * w1b.y + x1.z * w1b.z + x1.w * w1b.w;
        float p2 = x0.x * w2a.x + x0.y * w2a.y + x0.z * w2a.z + x0.w * w2a.w
                 + x1.x * w2b.x + x1.y * w2b.y + x1.z * w2b.z + x1.w * w2b.w;
        // Reduce across the 16-lane group (xor offsets < 16 stay in-group).
        #pragma unroll
        for (int off = 8; off > 0; off >>= 1) {
            p1 += __shfl_xor(p1, off, 64);
            p2 += __shfl_xor(p2, off, 64);
        }
        if (sl == 0) {
            s1[n] = p1;
            s2[n] = p2;
        }
    }
}

// Kernel 2: out[e] = s1[src[e]] + s2[dst[e]]; 8 edges per thread.
// Index streams: 2x int4 coalesced loads; gathers hit the 200KB L2-resident
// tables; output: 2x float4 coalesced stores.
__global__ __launch_bounds__(256) void edge_combine_kernel(
    const int* __restrict__ src,
    const int* __restrict__ dst,
    const float* __restrict__ s1,
    const float* __restrict__ s2,
    float* __restrict__ out,
    int n8)
{
    const int i = blockIdx.x * blockDim.x + threadIdx.x;
    if (i < n8) {
        const int4 sa = ((const int4*)src)[2 * i];
        const int4 sb = ((const int4*)src)[2 * i + 1];
        const int4 da = ((const int4*)dst)[2 * i];
        const int4 db = ((const int4*)dst)[2 * i + 1];
        float4 oa, ob;
        oa.x = s1[sa.x] + s2[da.x];
        oa.y = s1[sa.y] + s2[da.y];
        oa.z = s1[sa.z] + s2[da.z];
        oa.w = s1[sa.w] + s2[da.w];
        ob.x = s1[sb.x] + s2[db.x];
        ob.y = s1[sb.y] + s2[db.y];
        ob.z = s1[sb.z] + s2[db.z];
        ob.w = s1[sb.w] + s2[db.w];
        ((float4*)out)[2 * i]     = oa;
        ((float4*)out)[2 * i + 1] = ob;
    }
}

extern "C" void kernel_launch(void* const* d_in, const int* in_sizes, int n_in,
                              void* d_out, int out_size, void* d_ws, size_t ws_size,
                              hipStream_t stream) {
    const float* X  = (const float*)d_in[0];   // [N_NODES, D]
    const int*   ei = (const int*)d_in[1];     // [2, N_EDGES] (int32 on device)
    const float* W1 = (const float*)d_in[2];   // [1, D]
    const float* W2 = (const float*)d_in[3];   // [1, D]
    float* out = (float*)d_out;                // [N_EDGES, 1]

    // Workspace: two per-node scalar tables (fully overwritten each call).
    float* s1 = (float*)d_ws;
    float* s2 = s1 + N_NODES;

    // Kernel 1: 1024 blocks x 4 waves x 4 groups = 16384 groups (~3 nodes
    // each); 16 waves/CU so the X stream is BW-bound, not latency-bound.
    const int blocks1 = 1024;
    node_scores_kernel<<<blocks1, 256, 0, stream>>>(X, W1, W2, s1, s2,
                                                    N_NODES, blocks1 * 16);

    // Kernel 2: 80000 threads (8 edges each) -> 313 blocks of 256.
    const int n8 = N_EDGES / 8;
    edge_combine_kernel<<<(n8 + 255) / 256, 256, 0, stream>>>(
        ei, ei + N_EDGES, s1, s2, out, n8);
}